// Round 14
// baseline (732.785 us; speedup 1.0000x reference)
//
#include <hip/hip_runtime.h>

// GCN 2-layer + pool + head. R14 = R13 with the segmented-reduce boundary bug fixed:
// leader = (first edge in block) OR (col differs from previous in-block edge). Runs that
// span blocks contribute one partial atomic per block — correct and still ~150K atomics
// per layer vs 3.2M (the 19.6G/s RMW wall costs 163us/layer; reads ride free).
//   h[c] = b + dinv[c]*( g[c] + sum_e w_e * g[row_e] ),  g = dinv * (prev @ W)

#define SH 6
#define RB 64
#define KMAX 2048           // N <= 131072 (row packs in 17 bits)
#define TPB 256
#define BCAP 8192           // per-bucket LDS sort capacity (64KB)

// ---------- bucket counts ----------
__global__ void k_cnt(const int* __restrict__ col, unsigned* __restrict__ bcnt, int E, int K) {
    __shared__ unsigned lh[KMAX];
    for (int i = threadIdx.x; i < K; i += blockDim.x) lh[i] = 0u;
    __syncthreads();
    for (long long e = (long long)blockIdx.x * blockDim.x + threadIdx.x; e < E;
         e += (long long)gridDim.x * blockDim.x)
        atomicAdd(&lh[col[e] >> SH], 1u);
    __syncthreads();
    for (int i = threadIdx.x; i < K; i += blockDim.x)
        if (lh[i]) atomicAdd(&bcnt[i], lh[i]);
}

// ---------- exclusive scan -> bst, bcur ----------
__global__ void k_scan(const unsigned* __restrict__ cnt, unsigned* __restrict__ start,
                       unsigned* __restrict__ cursor, int K) {
    __shared__ unsigned a[KMAX], b[KMAX];
    int t = threadIdx.x;  // 1024
    for (int i = t; i < KMAX; i += 1024) a[i] = (i < K) ? cnt[i] : 0u;
    __syncthreads();
    unsigned *src = a, *dst = b;
    for (int off = 1; off < KMAX; off <<= 1) {
        for (int i = t; i < KMAX; i += 1024)
            dst[i] = (i >= off) ? src[i] + src[i - off] : src[i];
        __syncthreads();
        unsigned* tmp = src; src = dst; dst = tmp;
    }
    for (int i = t; i < K; i += 1024) {
        unsigned ex = (i == 0) ? 0u : src[i - 1];
        start[i] = ex; cursor[i] = ex;
    }
}

// ---------- bin scatter: brcw[pos] = (row | cl<<17, w_f32) ----------
__global__ __launch_bounds__(512)
void k_binsc(const int* __restrict__ row, const int* __restrict__ col,
             const float* __restrict__ w, unsigned* __restrict__ bcur,
             uint2* __restrict__ brcw, int E, int K) {
    __shared__ unsigned lh[KMAX];
    int tile = (E + gridDim.x - 1) / gridDim.x;
    int e0 = blockIdx.x * tile, e1 = min(e0 + tile, E);
    for (int i = threadIdx.x; i < K; i += 512) lh[i] = 0u;
    __syncthreads();
    for (int e = e0 + threadIdx.x; e < e1; e += 512) atomicAdd(&lh[col[e] >> SH], 1u);
    __syncthreads();
    for (int i = threadIdx.x; i < K; i += 512) {
        unsigned c = lh[i];
        lh[i] = c ? atomicAdd(&bcur[i], c) : 0u;
    }
    __syncthreads();
    for (int e = e0 + threadIdx.x; e < e1; e += 512) {
        int c = col[e];
        unsigned pos = atomicAdd(&lh[c >> SH], 1u);
        brcw[pos] = make_uint2((unsigned)row[e] | ((unsigned)(c & 63) << 17),
                               __float_as_uint(w[e]));
    }
}

// ---------- per-bucket: counting sort by col (in-place) + deg/dinv + g1/acc1 seed ----------
// output payload: (col_full, row | wq15<<17), wq15 = round(w*32768) clamped to 32767
__global__ __launch_bounds__(TPB)
void k_bsort(uint2* __restrict__ brcw, const unsigned* __restrict__ bst,
             const unsigned* __restrict__ bcnt, const float* __restrict__ x,
             const float* __restrict__ W1, float* __restrict__ dinv,
             float* __restrict__ g1, float* __restrict__ acc1, int N) {
    int k = blockIdx.x, node0 = k << SH;
    __shared__ uint2 ebuf[BCAP];            // 64KB
    __shared__ unsigned cnt64[RB], st64[RB], dq[RB];
    __shared__ float dl[RB], lx[RB * 3], lw[48];
    int tid = threadIdx.x;
    unsigned s = bst[k], c = bcnt[k];
    if (tid < RB) { cnt64[tid] = 0u; dq[tid] = 0u; }
    if (tid < 48) lw[tid] = W1[tid];
    int nn = min(RB, N - node0);
    for (int i = tid; i < nn * 3; i += TPB) lx[i] = x[(size_t)node0 * 3 + i];
    __syncthreads();

    bool fits = (c <= (unsigned)BCAP);
    if (fits) {
        for (unsigned j = tid; j < c; j += TPB) {
            uint2 p = brcw[s + j];
            unsigned cl = (p.x >> 17) & 63u;
            unsigned wq = (unsigned)__float2int_rn(__uint_as_float(p.y) * 32768.0f);
            wq = wq > 32767u ? 32767u : wq;
            p.y = (p.x & 0x1FFFFu) | (wq << 17);       // row | wq15
            p.x = (unsigned)(node0 + (int)cl);          // full col
            ebuf[j] = p;
            atomicAdd(&cnt64[cl], 1u);
            atomicAdd(&dq[cl], wq);
        }
        __syncthreads();
        if (tid == 0) {                                  // tiny serial scan of 64
            unsigned acc = 0;
            for (int i = 0; i < RB; i++) { st64[i] = acc; acc += cnt64[i]; cnt64[i] = 0u; }
        }
        __syncthreads();
        for (unsigned j = tid; j < c; j += TPB) {
            uint2 p = ebuf[j];
            unsigned cl = p.x - (unsigned)node0;
            unsigned pos = st64[cl] + atomicAdd(&cnt64[cl], 1u);
            brcw[s + pos] = p;
        }
    } else {
        // fallback: convert payload in place (unsorted — consumer stays correct)
        for (unsigned j = tid; j < c; j += TPB) {
            uint2 p = brcw[s + j];
            unsigned cl = (p.x >> 17) & 63u;
            unsigned wq = (unsigned)__float2int_rn(__uint_as_float(p.y) * 32768.0f);
            wq = wq > 32767u ? 32767u : wq;
            p.y = (p.x & 0x1FFFFu) | (wq << 17);
            p.x = (unsigned)(node0 + (int)cl);
            brcw[s + j] = p;
            atomicAdd(&dq[cl], wq);
        }
    }
    __syncthreads();
    if (tid < RB) {
        float d = rsqrtf(1.0f + (float)dq[tid] * (1.0f / 32768.0f));  // self-loop +1
        dl[tid] = d;
        if (tid < nn) dinv[node0 + tid] = d;
    }
    __syncthreads();
    for (int idx = tid; idx < nn * 16; idx += TPB) {
        int n = idx >> 4, f = idx & 15;
        float d = dl[n];
        float v = d * (lx[n * 3] * lw[f] + lx[n * 3 + 1] * lw[16 + f] +
                       lx[n * 3 + 2] * lw[32 + f]);
        g1[(size_t)(node0 + n) * 16 + f] = v;
        acc1[(size_t)(node0 + n) * 16 + f] = v;
    }
}

// ---------- FLAT gather + per-block segmented reduce: 64 edges/block, 16 lanes/edge ----------
// leader = first edge in block OR col differs from previous in-block edge; each block adds
// its partial run-sums (spanning runs -> one atomic per block, correct).
__global__ __launch_bounds__(1024)
void k_gath(const uint2* __restrict__ srt, const float* __restrict__ g,
            float* __restrict__ acc, int E) {
    __shared__ uint2 se[64];
    __shared__ float vbuf[64][16];
    int tid = threadIdx.x;
    long long e0 = (long long)blockIdx.x * 64;
    if (tid < 64) {
        long long e = e0 + tid;
        se[tid] = (e < E) ? srt[e] : make_uint2(0xFFFFFFFFu, 0u);
    }
    __syncthreads();
    int le = tid >> 4, f = tid & 15;
    long long e = e0 + le;
    uint2 m = se[le];
    float v = 0.0f;
    if (e < E) {
        unsigned r = m.y & 0x1FFFFu;
        float w = (float)(m.y >> 17) * (1.0f / 32768.0f);
        v = w * g[(size_t)r * 16 + f];               // THE random gather (1 line/edge)
    }
    vbuf[le][f] = v;
    __syncthreads();
    if (e < E) {
        bool leader = (le == 0) || (se[le - 1].x != m.x);
        if (leader) {
            float sum = v;
            for (int j = le + 1; j < 64 && se[j].x == m.x; j++) sum += vbuf[j][f];
            atomicAdd(&acc[(size_t)m.x * 16 + f], sum);  // ~2-3 per block
        }
    }
}

// ---------- mid: h1 = relu(b1 + dinv*acc1); g2 = dinv*(h1@W2); acc2 seeded = g2 ----------
__global__ void k_mid(const float* __restrict__ acc1, const float* __restrict__ dinv,
                      const float* __restrict__ b1, const float* __restrict__ W2,
                      float* __restrict__ g2, float* __restrict__ acc2, int N) {
    __shared__ float t[16][16];
    __shared__ float w2[256];
    int tid = threadIdx.x;
    int il = tid >> 4, f = tid & 15;
    int i = blockIdx.x * 16 + il;
    w2[tid] = W2[tid];
    float v = 0.0f, d = 0.0f;
    if (i < N) {
        d = dinv[i];
        v = b1[f] + d * acc1[(size_t)i * 16 + f];
        v = v > 0.0f ? v : 0.0f;
    }
    t[il][f] = v;
    __syncthreads();
    if (i < N) {
        float o = 0.0f;
#pragma unroll
        for (int kk = 0; kk < 16; kk++) o += t[il][kk] * w2[kk * 16 + f];
        float r = d * o;
        g2[(size_t)i * 16 + f] = r;
        acc2[(size_t)i * 16 + f] = r;
    }
}

// ---------- pool: h2 = relu(b2 + dinv*acc2) folded into sorted-batch pool ----------
#define PC 1024
__global__ void k_pool(const float* __restrict__ acc2, const float* __restrict__ dinv,
                       const float* __restrict__ b2, const int* __restrict__ batch,
                       float* __restrict__ pooled, int N, int G) {
    int b0 = blockIdx.x * PC;
    int nodes = min(PC, N - b0);
    __shared__ float lacc[64 * 16];
    __shared__ int lbat[PC];
    int tid = threadIdx.x;  // 256
    for (int i = tid; i < nodes; i += 256) lbat[i] = batch[b0 + i];
    __syncthreads();
    int gmin = lbat[0], gmax = lbat[nodes - 1];
    bool fits = (gmax - gmin < 64);
    if (fits) {
        for (int i = tid; i < 64 * 16; i += 256) lacc[i] = 0.0f;
        __syncthreads();
    }
    for (int idx = tid; idx < nodes * 16; idx += 256) {
        int i = idx >> 4, f = idx & 15;
        int n = b0 + i;
        float d = dinv[n];
        float v = b2[f] + d * acc2[(size_t)n * 16 + f];
        v = v > 0.0f ? v : 0.0f;
        if (fits) atomicAdd(&lacc[(lbat[i] - gmin) * 16 + f], v);
        else      atomicAdd(&pooled[lbat[i] * 16 + f], v);
    }
    if (fits) {
        __syncthreads();
        for (int idx = tid; idx < 64 * 16; idx += 256) {
            int g = gmin + (idx >> 4);
            float v = lacc[idx];
            if (g < G && v != 0.0f) atomicAdd(&pooled[g * 16 + (idx & 15)], v);
        }
    }
}

__global__ void k_final(const float* __restrict__ pooled, const float* __restrict__ Wlin,
                        const float* __restrict__ blin, float* __restrict__ out, int G) {
    int t = blockIdx.x * blockDim.x + threadIdx.x;
    int g = t / 7, j = t % 7;
    if (g >= G) return;
    float v = blin[j];
#pragma unroll
    for (int f = 0; f < 16; f++) v += pooled[g * 16 + f] * Wlin[f * 7 + j];
    out[g * 7 + j] = v;
}

static inline int cdiv_i(long long a, long long b) { return (int)((a + b - 1) / b); }

extern "C" void kernel_launch(void* const* d_in, const int* in_sizes, int n_in,
                              void* d_out, int out_size, void* d_ws, size_t ws_size,
                              hipStream_t stream) {
    const float* x     = (const float*)d_in[0];
    const int*   ei    = (const int*)d_in[1];
    const float* ew    = (const float*)d_in[2];
    const int*   batch = (const int*)d_in[3];
    const float* W1    = (const float*)d_in[4];
    const float* b1    = (const float*)d_in[5];
    const float* W2    = (const float*)d_in[6];
    const float* b2    = (const float*)d_in[7];
    const float* Wlin  = (const float*)d_in[8];
    const float* blin  = (const float*)d_in[9];
    float* out = (float*)d_out;

    const int N = in_sizes[0] / 3;
    const int E = in_sizes[2];
    const int G = out_size / 7;
    const int K = (N + RB - 1) >> SH;   // 1563
    const int* row = ei;
    const int* col = ei + E;

    // layout: brcw | [zero: bcnt, bcur, pooled] | bst | dinv | g1 | acc1 | g2 | acc2
    uint2*    brcw   = (uint2*)d_ws;                        // E (binned, then sorted in-place)
    unsigned* bcnt   = (unsigned*)(brcw + E);               // KMAX
    unsigned* bcur   = bcnt + KMAX;                         // KMAX
    float*    pooled = (float*)(bcur + KMAX);               // G*16
    unsigned* bst    = (unsigned*)(pooled + (size_t)G*16);  // KMAX
    float*    dinv   = (float*)(bst + KMAX);                // N
    float*    g1     = dinv + N;                            // N*16
    float*    acc1   = g1 + (size_t)N * 16;                 // N*16
    float*    g2     = acc1 + (size_t)N * 16;               // N*16
    float*    acc2   = g2 + (size_t)N * 16;                 // N*16

    hipMemsetAsync(bcnt, 0, (2 * KMAX + (size_t)G * 16) * sizeof(unsigned), stream);

    // sort edges by col (two-level counting sort)
    k_cnt<<<256, TPB, 0, stream>>>(col, bcnt, E, K);
    k_scan<<<1, 1024, 0, stream>>>(bcnt, bst, bcur, K);
    k_binsc<<<64, 512, 0, stream>>>(row, col, ew, bcur, brcw, E, K);
    k_bsort<<<K, TPB, 0, stream>>>(brcw, bst, bcnt, x, W1, dinv, g1, acc1, N);

    // layer 1: flat gather + per-block segmented reduce
    k_gath<<<cdiv_i(E, 64), 1024, 0, stream>>>(brcw, g1, acc1, E);

    // mid: h1 -> g2; acc2 pre-seeded
    k_mid<<<cdiv_i(N, 16), TPB, 0, stream>>>(acc1, dinv, b1, W2, g2, acc2, N);

    // layer 2
    k_gath<<<cdiv_i(E, 64), 1024, 0, stream>>>(brcw, g2, acc2, E);

    // pool + head
    k_pool<<<cdiv_i(N, PC), TPB, 0, stream>>>(acc2, dinv, b2, batch, pooled, N, G);
    k_final<<<cdiv_i((long long)G * 7, TPB), TPB, 0, stream>>>(pooled, Wlin, blin, out, G);
}

// Round 15
// 461.302 us; speedup vs baseline: 1.5885x; 1.5885x over previous
//
#include <hip/hip_runtime.h>

// GCN 2-layer + pool + head via col-sorted edges + flat segmented-reduce consumer.
// R15 = R14 with the consumer micro-shape fixed (R14: 1024-thr blocks -> 1.1 resident/CU,
// serial leader loop -> 222us): 256-thr blocks / 32 edges (8 resident/CU), 5-step parallel
// segmented scan, bf16 g-table (3.2MB -> L2-resident gathers, 8 lanes/edge).
//   h[c] = b + dinv[c]*( g[c] + sum_e w_e * g[row_e] ),  g = dinv * (prev @ W)

#define SH 6
#define RB 64
#define KMAX 2048           // N <= 131072 (row packs in 17 bits)
#define TPB 256
#define BCAP 8192           // per-bucket LDS sort capacity (64KB)
#define GT 32               // edges per k_gath block

typedef unsigned short ushort_t;

__device__ __forceinline__ ushort_t f2bf(float v) {
    unsigned u = __float_as_uint(v);
    u += 0x7FFFu + ((u >> 16) & 1u);   // RNE
    return (ushort_t)(u >> 16);
}

// ---------- bucket counts ----------
__global__ void k_cnt(const int* __restrict__ col, unsigned* __restrict__ bcnt, int E, int K) {
    __shared__ unsigned lh[KMAX];
    for (int i = threadIdx.x; i < K; i += blockDim.x) lh[i] = 0u;
    __syncthreads();
    for (long long e = (long long)blockIdx.x * blockDim.x + threadIdx.x; e < E;
         e += (long long)gridDim.x * blockDim.x)
        atomicAdd(&lh[col[e] >> SH], 1u);
    __syncthreads();
    for (int i = threadIdx.x; i < K; i += blockDim.x)
        if (lh[i]) atomicAdd(&bcnt[i], lh[i]);
}

// ---------- exclusive scan -> bst, bcur ----------
__global__ void k_scan(const unsigned* __restrict__ cnt, unsigned* __restrict__ start,
                       unsigned* __restrict__ cursor, int K) {
    __shared__ unsigned a[KMAX], b[KMAX];
    int t = threadIdx.x;  // 1024
    for (int i = t; i < KMAX; i += 1024) a[i] = (i < K) ? cnt[i] : 0u;
    __syncthreads();
    unsigned *src = a, *dst = b;
    for (int off = 1; off < KMAX; off <<= 1) {
        for (int i = t; i < KMAX; i += 1024)
            dst[i] = (i >= off) ? src[i] + src[i - off] : src[i];
        __syncthreads();
        unsigned* tmp = src; src = dst; dst = tmp;
    }
    for (int i = t; i < K; i += 1024) {
        unsigned ex = (i == 0) ? 0u : src[i - 1];
        start[i] = ex; cursor[i] = ex;
    }
}

// ---------- bin scatter: brcw[pos] = (row | cl<<17, w_f32) ----------
__global__ __launch_bounds__(512)
void k_binsc(const int* __restrict__ row, const int* __restrict__ col,
             const float* __restrict__ w, unsigned* __restrict__ bcur,
             uint2* __restrict__ brcw, int E, int K) {
    __shared__ unsigned lh[KMAX];
    int tile = (E + gridDim.x - 1) / gridDim.x;
    int e0 = blockIdx.x * tile, e1 = min(e0 + tile, E);
    for (int i = threadIdx.x; i < K; i += 512) lh[i] = 0u;
    __syncthreads();
    for (int e = e0 + threadIdx.x; e < e1; e += 512) atomicAdd(&lh[col[e] >> SH], 1u);
    __syncthreads();
    for (int i = threadIdx.x; i < K; i += 512) {
        unsigned c = lh[i];
        lh[i] = c ? atomicAdd(&bcur[i], c) : 0u;
    }
    __syncthreads();
    for (int e = e0 + threadIdx.x; e < e1; e += 512) {
        int c = col[e];
        unsigned pos = atomicAdd(&lh[c >> SH], 1u);
        brcw[pos] = make_uint2((unsigned)row[e] | ((unsigned)(c & 63) << 17),
                               __float_as_uint(w[e]));
    }
}

// ---------- per-bucket: counting sort by col (in-place) + deg/dinv + g1(bf16)/acc1 seed ----
// output payload: (col_full, row | wq15<<17), wq15 = round(w*32768) clamped to 32767
__global__ __launch_bounds__(TPB)
void k_bsort(uint2* __restrict__ brcw, const unsigned* __restrict__ bst,
             const unsigned* __restrict__ bcnt, const float* __restrict__ x,
             const float* __restrict__ W1, float* __restrict__ dinv,
             unsigned* __restrict__ g1b, float* __restrict__ acc1, int N) {
    int k = blockIdx.x, node0 = k << SH;
    __shared__ uint2 ebuf[BCAP];            // 64KB (reused as gtmp after sort)
    __shared__ unsigned cnt64[RB], st64[RB], dq[RB];
    __shared__ float dl[RB], lx[RB * 3], lw[48];
    int tid = threadIdx.x;
    unsigned s = bst[k], c = bcnt[k];
    if (tid < RB) { cnt64[tid] = 0u; dq[tid] = 0u; }
    if (tid < 48) lw[tid] = W1[tid];
    int nn = min(RB, N - node0);
    for (int i = tid; i < nn * 3; i += TPB) lx[i] = x[(size_t)node0 * 3 + i];
    __syncthreads();

    bool fits = (c <= (unsigned)BCAP);
    if (fits) {
        for (unsigned j = tid; j < c; j += TPB) {
            uint2 p = brcw[s + j];
            unsigned cl = (p.x >> 17) & 63u;
            unsigned wq = (unsigned)__float2int_rn(__uint_as_float(p.y) * 32768.0f);
            wq = wq > 32767u ? 32767u : wq;
            p.y = (p.x & 0x1FFFFu) | (wq << 17);       // row | wq15
            p.x = (unsigned)(node0 + (int)cl);          // full col
            ebuf[j] = p;
            atomicAdd(&cnt64[cl], 1u);
            atomicAdd(&dq[cl], wq);
        }
        __syncthreads();
        if (tid == 0) {                                  // tiny serial scan of 64
            unsigned acc = 0;
            for (int i = 0; i < RB; i++) { st64[i] = acc; acc += cnt64[i]; cnt64[i] = 0u; }
        }
        __syncthreads();
        for (unsigned j = tid; j < c; j += TPB) {
            uint2 p = ebuf[j];
            unsigned cl = p.x - (unsigned)node0;
            unsigned pos = st64[cl] + atomicAdd(&cnt64[cl], 1u);
            brcw[s + pos] = p;
        }
    } else {
        for (unsigned j = tid; j < c; j += TPB) {        // fallback: unsorted passthrough
            uint2 p = brcw[s + j];
            unsigned cl = (p.x >> 17) & 63u;
            unsigned wq = (unsigned)__float2int_rn(__uint_as_float(p.y) * 32768.0f);
            wq = wq > 32767u ? 32767u : wq;
            p.y = (p.x & 0x1FFFFu) | (wq << 17);
            p.x = (unsigned)(node0 + (int)cl);
            brcw[s + j] = p;
            atomicAdd(&dq[cl], wq);
        }
    }
    __syncthreads();
    if (tid < RB) {
        float d = rsqrtf(1.0f + (float)dq[tid] * (1.0f / 32768.0f));  // self-loop +1
        dl[tid] = d;
        if (tid < nn) dinv[node0 + tid] = d;
    }
    __syncthreads();
    float* gtmp = (float*)ebuf;   // safe: ebuf reads all complete
    for (int idx = tid; idx < nn * 16; idx += TPB) {
        int n = idx >> 4, f = idx & 15;
        float v = dl[n] * (lx[n * 3] * lw[f] + lx[n * 3 + 1] * lw[16 + f] +
                           lx[n * 3 + 2] * lw[32 + f]);
        acc1[(size_t)(node0 + n) * 16 + f] = v;
        gtmp[idx] = v;
    }
    __syncthreads();
    for (int idx = tid; idx < nn * 8; idx += TPB) {
        int n = idx >> 3, q = idx & 7;
        float a = gtmp[n * 16 + 2 * q], b = gtmp[n * 16 + 2 * q + 1];
        g1b[(size_t)(node0 + n) * 8 + q] = (unsigned)f2bf(a) | ((unsigned)f2bf(b) << 16);
    }
}

// ---------- consumer: 32 edges/block, 8 lanes/edge, parallel segmented scan ----------
__global__ __launch_bounds__(TPB)
void k_gath(const uint2* __restrict__ srt, const unsigned* __restrict__ gb,
            float* __restrict__ acc, int E) {
    __shared__ uint2 se[GT];
    __shared__ float vx[GT][8], vy[GT][8];
    int tid = threadIdx.x;
    long long e0 = (long long)blockIdx.x * GT;
    if (tid < GT) {
        long long e = e0 + tid;
        se[tid] = (e < E) ? srt[e] : make_uint2(0xFFFFFFFFu, 0u);
    }
    __syncthreads();
    int le = tid >> 3, f2 = tid & 7;
    uint2 m = se[le];
    long long e = e0 + le;
    float a = 0.0f, b = 0.0f;
    if (e < E) {
        unsigned r = m.y & 0x1FFFFu;
        float w = (float)(m.y >> 17) * (1.0f / 32768.0f);
        unsigned u = gb[(size_t)r * 8 + f2];     // bf16x2 gather — L2-resident table
        a = w * __uint_as_float(u << 16);
        b = w * __uint_as_float(u & 0xFFFF0000u);
    }
    vx[le][f2] = a; vy[le][f2] = b;
    __syncthreads();
#pragma unroll
    for (int s = 1; s < GT; s <<= 1) {           // segmented inclusive scan over le
        float ax = 0.0f, ay = 0.0f;
        if (le >= s && se[le - s].x == m.x) { ax = vx[le - s][f2]; ay = vy[le - s][f2]; }
        __syncthreads();
        vx[le][f2] += ax; vy[le][f2] += ay;
        __syncthreads();
    }
    if (e < E) {
        bool last = (le == GT - 1) || (se[le + 1].x != m.x);   // end of contiguous run-piece
        if (last) {
            atomicAdd(&acc[(size_t)m.x * 16 + 2 * f2],     vx[le][f2]);
            atomicAdd(&acc[(size_t)m.x * 16 + 2 * f2 + 1], vy[le][f2]);
        }
    }
}

// ---------- mid: h1 = relu(b1 + dinv*acc1); g2 = dinv*(h1@W2) -> bf16 + acc2 seed ----------
__global__ void k_mid(const float* __restrict__ acc1, const float* __restrict__ dinv,
                      const float* __restrict__ b1, const float* __restrict__ W2,
                      unsigned* __restrict__ g2b, float* __restrict__ acc2, int N) {
    __shared__ float t[16][16];
    __shared__ float go[16][16];
    __shared__ float w2[256];
    int tid = threadIdx.x;
    int il = tid >> 4, f = tid & 15;
    int i = blockIdx.x * 16 + il;
    w2[tid] = W2[tid];
    float v = 0.0f, d = 0.0f;
    if (i < N) {
        d = dinv[i];
        v = b1[f] + d * acc1[(size_t)i * 16 + f];
        v = v > 0.0f ? v : 0.0f;
    }
    t[il][f] = v;
    __syncthreads();
    float r = 0.0f;
    if (i < N) {
        float o = 0.0f;
#pragma unroll
        for (int kk = 0; kk < 16; kk++) o += t[il][kk] * w2[kk * 16 + f];
        r = d * o;
        acc2[(size_t)i * 16 + f] = r;
    }
    go[il][f] = r;
    __syncthreads();
    if (tid < 128) {
        int il2 = tid >> 3, q = tid & 7;
        int i2 = blockIdx.x * 16 + il2;
        if (i2 < N)
            g2b[(size_t)i2 * 8 + q] = (unsigned)f2bf(go[il2][2 * q]) |
                                      ((unsigned)f2bf(go[il2][2 * q + 1]) << 16);
    }
}

// ---------- pool: h2 = relu(b2 + dinv*acc2) folded into sorted-batch pool ----------
#define PC 1024
__global__ void k_pool(const float* __restrict__ acc2, const float* __restrict__ dinv,
                       const float* __restrict__ b2, const int* __restrict__ batch,
                       float* __restrict__ pooled, int N, int G) {
    int b0 = blockIdx.x * PC;
    int nodes = min(PC, N - b0);
    __shared__ float lacc[64 * 16];
    __shared__ int lbat[PC];
    int tid = threadIdx.x;  // 256
    for (int i = tid; i < nodes; i += 256) lbat[i] = batch[b0 + i];
    __syncthreads();
    int gmin = lbat[0], gmax = lbat[nodes - 1];
    bool fits = (gmax - gmin < 64);
    if (fits) {
        for (int i = tid; i < 64 * 16; i += 256) lacc[i] = 0.0f;
        __syncthreads();
    }
    for (int idx = tid; idx < nodes * 16; idx += 256) {
        int i = idx >> 4, f = idx & 15;
        int n = b0 + i;
        float d = dinv[n];
        float v = b2[f] + d * acc2[(size_t)n * 16 + f];
        v = v > 0.0f ? v : 0.0f;
        if (fits) atomicAdd(&lacc[(lbat[i] - gmin) * 16 + f], v);
        else      atomicAdd(&pooled[lbat[i] * 16 + f], v);
    }
    if (fits) {
        __syncthreads();
        for (int idx = tid; idx < 64 * 16; idx += 256) {
            int g = gmin + (idx >> 4);
            float v = lacc[idx];
            if (g < G && v != 0.0f) atomicAdd(&pooled[g * 16 + (idx & 15)], v);
        }
    }
}

__global__ void k_final(const float* __restrict__ pooled, const float* __restrict__ Wlin,
                        const float* __restrict__ blin, float* __restrict__ out, int G) {
    int t = blockIdx.x * blockDim.x + threadIdx.x;
    int g = t / 7, j = t % 7;
    if (g >= G) return;
    float v = blin[j];
#pragma unroll
    for (int f = 0; f < 16; f++) v += pooled[g * 16 + f] * Wlin[f * 7 + j];
    out[g * 7 + j] = v;
}

static inline int cdiv_i(long long a, long long b) { return (int)((a + b - 1) / b); }

extern "C" void kernel_launch(void* const* d_in, const int* in_sizes, int n_in,
                              void* d_out, int out_size, void* d_ws, size_t ws_size,
                              hipStream_t stream) {
    const float* x     = (const float*)d_in[0];
    const int*   ei    = (const int*)d_in[1];
    const float* ew    = (const float*)d_in[2];
    const int*   batch = (const int*)d_in[3];
    const float* W1    = (const float*)d_in[4];
    const float* b1    = (const float*)d_in[5];
    const float* W2    = (const float*)d_in[6];
    const float* b2    = (const float*)d_in[7];
    const float* Wlin  = (const float*)d_in[8];
    const float* blin  = (const float*)d_in[9];
    float* out = (float*)d_out;

    const int N = in_sizes[0] / 3;
    const int E = in_sizes[2];
    const int G = out_size / 7;
    const int K = (N + RB - 1) >> SH;   // 1563
    const int* row = ei;
    const int* col = ei + E;

    // layout: brcw | [zero: bcnt, bcur, pooled] | bst | dinv | g1b | g2b | acc1 | acc2
    uint2*    brcw   = (uint2*)d_ws;                        // E
    unsigned* bcnt   = (unsigned*)(brcw + E);               // KMAX
    unsigned* bcur   = bcnt + KMAX;                         // KMAX
    float*    pooled = (float*)(bcur + KMAX);               // G*16
    unsigned* bst    = (unsigned*)(pooled + (size_t)G*16);  // KMAX
    float*    dinv   = (float*)(bst + KMAX);                // N
    unsigned* g1b    = (unsigned*)(dinv + N);               // N*8 (bf16 x16)
    unsigned* g2b    = g1b + (size_t)N * 8;                 // N*8
    float*    acc1   = (float*)(g2b + (size_t)N * 8);       // N*16
    float*    acc2   = acc1 + (size_t)N * 16;               // N*16

    hipMemsetAsync(bcnt, 0, (2 * KMAX + (size_t)G * 16) * sizeof(unsigned), stream);

    // sort edges by col (two-level counting sort)
    k_cnt<<<256, TPB, 0, stream>>>(col, bcnt, E, K);
    k_scan<<<1, 1024, 0, stream>>>(bcnt, bst, bcur, K);
    k_binsc<<<128, 512, 0, stream>>>(row, col, ew, bcur, brcw, E, K);
    k_bsort<<<K, TPB, 0, stream>>>(brcw, bst, bcnt, x, W1, dinv, g1b, acc1, N);

    // layer 1: flat gather + parallel segmented reduce
    k_gath<<<cdiv_i(E, GT), TPB, 0, stream>>>(brcw, g1b, acc1, E);

    // mid: h1 -> g2(bf16) + acc2 seed
    k_mid<<<cdiv_i(N, 16), TPB, 0, stream>>>(acc1, dinv, b1, W2, g2b, acc2, N);

    // layer 2
    k_gath<<<cdiv_i(E, GT), TPB, 0, stream>>>(brcw, g2b, acc2, E);

    // pool + head
    k_pool<<<cdiv_i(N, PC), TPB, 0, stream>>>(acc2, dinv, b2, batch, pooled, N, G);
    k_final<<<cdiv_i((long long)G * 7, TPB), TPB, 0, stream>>>(pooled, Wlin, blin, out, G);
}